// Round 1
// 1228.008 us; speedup vs baseline: 1.1209x; 1.1209x over previous
//
#include <hip/hip_runtime.h>
#include <hip/hip_bf16.h>
#include <cstdint>

typedef unsigned short ushort_t;
typedef __attribute__((ext_vector_type(8))) short bf16x8;
typedef __attribute__((ext_vector_type(4))) float f32x4;

#define LSEQ 2048
#define DIM 3072
#define NFUSE 21504   // 3*DIM + MLP
#define NCOMB 15360   // DIM + MLP
#define HEADS 24
#define HD 128

__device__ __forceinline__ float b2f(ushort_t u) {
    union { float f; unsigned v; } x; x.v = ((unsigned)u) << 16; return x.f;
}
__device__ __forceinline__ ushort_t f2b(float f) {
    union { float f; unsigned v; } x; x.f = f;
    unsigned r = (x.v + 0x7FFF + ((x.v >> 16) & 1)) >> 16;
    return (ushort_t)r;
}
__device__ __forceinline__ void async_cp16(const void* g, void* l) {
    __builtin_amdgcn_global_load_lds(
        (const __attribute__((address_space(1))) void*)g,
        (__attribute__((address_space(3))) void*)l, 16, 0, 0);
}

// ---------------- f32 -> bf16 cast (weights) ----------------
__global__ __launch_bounds__(256)
void cast_f2b(const float* __restrict__ src, ushort_t* __restrict__ dst)
{
    size_t i = ((size_t)blockIdx.x * 256 + threadIdx.x) * 4;
    float4 v = *(const float4*)(src + i);
    ushort_t o[4] = { f2b(v.x), f2b(v.y), f2b(v.z), f2b(v.w) };
    *(uint2*)(dst + i) = *(uint2*)o;
}

// ---------------- LayerNorm + modulation (f32 in, bf16 out) ----------------
__global__ __launch_bounds__(256)
void ln_mod(const float* __restrict__ x, const float* __restrict__ msc,
            const float* __restrict__ msh, ushort_t* __restrict__ xmod)
{
    int l = blockIdx.x, t = threadIdx.x;
    const float* xr = x + (size_t)l * DIM;
    float v[12]; float s = 0.f;
    for (int i = 0; i < 12; ++i) { v[i] = xr[t + i * 256]; s += v[i]; }
    for (int off = 1; off <= 32; off <<= 1) s += __shfl_xor(s, off, 64);
    __shared__ float red[8];
    int w = t >> 6;
    if ((t & 63) == 0) red[w] = s;
    __syncthreads();
    s = red[0] + red[1] + red[2] + red[3];
    float mu = s * (1.f / DIM);
    float vs = 0.f;
    for (int i = 0; i < 12; ++i) { float d = v[i] - mu; vs += d * d; }
    for (int off = 1; off <= 32; off <<= 1) vs += __shfl_xor(vs, off, 64);
    if ((t & 63) == 0) red[4 + w] = vs;
    __syncthreads();
    vs = red[4] + red[5] + red[6] + red[7];
    float rinv = rsqrtf(vs * (1.f / DIM) + 1e-6f);
    ushort_t* orow = xmod + (size_t)l * DIM;
    for (int i = 0; i < 12; ++i) {
        int c = t + i * 256;
        float m = (v[i] - mu) * rinv;
        orow[c] = f2b((1.f + msc[c]) * m + msh[c]);
    }
}

// ============ 256x256-tile, BK=64, 8-wave, 8-phase pipelined GEMM =============
// C[M,N] = A[M,K] * B[N,K]^T.  MODE 0: bf16 C + bias.  MODE 2: f32 split-K
// partials (z<5 -> Cv, z>=5 -> Cv2).  Requires M%256==0, N%256==0,
// kchunk%128==0 (NT even, NT>=2), grid.x*grid.y % 8 == 0.
//
// LDS (128 KiB): buf b at b*32768 ushorts; A at +0, B at +16384.
// Chunk = 16 rows x 32 cols bf16 = 1 KiB = one wave64 global_load_lds x16 round.
// Within chunk: row-major [16][32]; per-lane src (srow,scol) pre-permuted so the
// linear LDS write order == ds_read_b128 consumption order (conflict-free:
// uniform 8 accesses/bank per wave64 b128 read).
//
// Per K-tile (4 phases; quadrants of the 8x4 per-wave frag grid):
//  ph1: ds_read A[m0-3] (8) + B[n0-1] (4); stage t+1 B-half0 -> nxt
//  ph2: ds_read B[n2-3] (4);               stage t+1 B-half1 -> nxt
//  ph3: ds_read A[m4-7] (8, reuse regs);   (no stage)
//  ph4: stage t+2 A-half0+half1 -> cur (safe: all reads of cur done at ph3 bar);
//       MFMA; s_waitcnt vmcnt(4); barrier   (t+1 fully landed, t+2 A in flight)
// Steady state: 8 loads issued/tile, vmcnt(4) leaves 2 half-tiles in flight.

#define CFENCE() asm volatile("" ::: "memory")
#define BARRIER() do { CFENCE(); __builtin_amdgcn_s_barrier(); CFENCE(); } while (0)
#define WAITL0() asm volatile("s_waitcnt lgkmcnt(0)" ::: "memory")

#define STAGE_A(bf, hf, kt) do { \
    const ushort_t* _s = Ag + (size_t)(hf) * 128 * Ks + (size_t)(kt) * 64; \
    async_cp16(_s,                   &Lds[(bf) * 32768 + (hf) * 4096 + stA]); \
    async_cp16(_s + (size_t)64 * Ks, &Lds[(bf) * 32768 + (hf) * 4096 + stA + 2048]); \
} while (0)

#define STAGE_B(bf, hf, kt) do { \
    const ushort_t* _s = Bg + (size_t)(hf) * 128 * Ks + (size_t)(kt) * 64; \
    async_cp16(_s,                   &Lds[(bf) * 32768 + (hf) * 4096 + stB]); \
    async_cp16(_s + (size_t)64 * Ks, &Lds[(bf) * 32768 + (hf) * 4096 + stB + 2048]); \
} while (0)

#define LDA_HALF(bf, mbase) do { \
    _Pragma("unroll") for (int _mt = 0; _mt < 4; ++_mt) { \
        af[_mt][0] = *(const bf16x8*)&Lds[(bf) * 32768 +        rdA + ((mbase) + _mt) * 512]; \
        af[_mt][1] = *(const bf16x8*)&Lds[(bf) * 32768 + 8192 + rdA + ((mbase) + _mt) * 512]; \
    } } while (0)

#define LDB_PAIR(bf, nbase) do { \
    _Pragma("unroll") for (int _nt = 0; _nt < 2; ++_nt) { \
        bfr[(nbase) + _nt][0] = *(const bf16x8*)&Lds[(bf) * 32768 +        rdB + ((nbase) + _nt) * 512]; \
        bfr[(nbase) + _nt][1] = *(const bf16x8*)&Lds[(bf) * 32768 + 8192 + rdB + ((nbase) + _nt) * 512]; \
    } } while (0)

#define MMAQ(mlo, nlo) do { \
    _Pragma("unroll") for (int _mt = 0; _mt < 4; ++_mt) \
    _Pragma("unroll") for (int _nt = 0; _nt < 2; ++_nt) { \
        acc[(mlo) + _mt][(nlo) + _nt] = __builtin_amdgcn_mfma_f32_16x16x32_bf16( \
            af[_mt][0], bfr[(nlo) + _nt][0], acc[(mlo) + _mt][(nlo) + _nt], 0, 0, 0); \
        acc[(mlo) + _mt][(nlo) + _nt] = __builtin_amdgcn_mfma_f32_16x16x32_bf16( \
            af[_mt][1], bfr[(nlo) + _nt][1], acc[(mlo) + _mt][(nlo) + _nt], 0, 0, 0); \
    } } while (0)

#define KTILE(cur, nxt, t) do { \
    int _t1 = ((t) + 1 < NT) ? (t) + 1 : NT - 1; \
    int _t2 = ((t) + 2 < NT) ? (t) + 2 : NT - 1; \
    /* phase 1 */ \
    LDA_HALF(cur, 0); LDB_PAIR(cur, 0); \
    STAGE_B(nxt, 0, _t1); \
    asm volatile("s_waitcnt lgkmcnt(8)" ::: "memory"); \
    BARRIER(); WAITL0(); \
    __builtin_amdgcn_s_setprio(1); MMAQ(0, 0); __builtin_amdgcn_s_setprio(0); \
    BARRIER(); \
    /* phase 2 */ \
    LDB_PAIR(cur, 2); \
    STAGE_B(nxt, 1, _t1); \
    BARRIER(); WAITL0(); \
    __builtin_amdgcn_s_setprio(1); MMAQ(0, 2); __builtin_amdgcn_s_setprio(0); \
    BARRIER(); \
    /* phase 3 */ \
    LDA_HALF(cur, 4); \
    BARRIER(); WAITL0(); \
    __builtin_amdgcn_s_setprio(1); MMAQ(4, 2); __builtin_amdgcn_s_setprio(0); \
    BARRIER(); \
    /* phase 4 (no ds_reads; stage into cur is safe after ph3 barrier) */ \
    STAGE_A(cur, 0, _t2); STAGE_A(cur, 1, _t2); \
    __builtin_amdgcn_s_setprio(1); MMAQ(4, 0); __builtin_amdgcn_s_setprio(0); \
    asm volatile("s_waitcnt vmcnt(4)" ::: "memory"); \
    BARRIER(); \
} while (0)

template<int MODE>
__global__ __launch_bounds__(512, 2)
void gemm8p(const ushort_t* __restrict__ A, const ushort_t* __restrict__ B,
            const float* __restrict__ bias, void* __restrict__ Cv,
            void* __restrict__ Cv2, int M, int N, int Ks, int kchunk)
{
    __shared__ ushort_t Lds[65536];   // 128 KiB
    const int lane = threadIdx.x & 63, w = threadIdx.x >> 6;
    const int quad = lane >> 4, l16 = lane & 15;
    const int srow = lane >> 2, scol = (lane & 3) * 8;
    const int wr = w >> 2, wc = w & 3;
    const int kcS = w & 1, rc0 = w >> 1;   // staging chunk assignment

    // XCD-aware swizzle (nwg % 8 == 0 for all launches here)
    int nwg = gridDim.x * gridDim.y;
    int id = blockIdx.y * gridDim.x + blockIdx.x;
    int cpx = nwg >> 3;
    int swz = (id & 7) * cpx + (id >> 3);
    int bn = swz % gridDim.x, bm = swz / gridDim.x;

    const int kbeg = blockIdx.z * kchunk;
    const int NT = kchunk >> 6;

    const ushort_t* Ag = A + (size_t)bm * 256 * Ks + (size_t)(rc0 * 16 + srow) * Ks
                           + kbeg + kcS * 32 + scol;
    const ushort_t* Bg = B + (size_t)bn * 256 * Ks + (size_t)(rc0 * 16 + srow) * Ks
                           + kbeg + kcS * 32 + scol;

    const int stA = kcS * 8192 + rc0 * 512 + lane * 8;
    const int stB = 16384 + stA;
    const int rdA = wr * 4096 + l16 * 32 + quad * 8;
    const int rdB = 16384 + wc * 2048 + l16 * 32 + quad * 8;

    f32x4 acc[8][4] = {};
    bf16x8 af[4][2], bfr[4][2];

    // prologue: tile0 A+B -> buf0, tile1 A -> buf1; drain tile0 (vmcnt(4))
    STAGE_A(0, 0, 0); STAGE_A(0, 1, 0);
    STAGE_B(0, 0, 0); STAGE_B(0, 1, 0);
    STAGE_A(1, 0, 1); STAGE_A(1, 1, 1);
    asm volatile("s_waitcnt vmcnt(4)" ::: "memory");
    BARRIER();

    for (int t = 0; t < NT; t += 2) {
        KTILE(0, 1, t);
        KTILE(1, 0, t + 1);
    }
    asm volatile("s_waitcnt vmcnt(0)" ::: "memory");

    if constexpr (MODE == 0) {
        ushort_t* C = (ushort_t*)Cv;
        #pragma unroll
        for (int mt = 0; mt < 8; ++mt) {
            int rg = bm * 256 + wr * 128 + mt * 16 + quad * 4;
            #pragma unroll
            for (int nt = 0; nt < 4; ++nt) {
                int cg = bn * 256 + wc * 64 + nt * 16 + l16;
                float bv = bias[cg];
                #pragma unroll
                for (int r = 0; r < 4; ++r)
                    C[(size_t)(rg + r) * N + cg] = f2b(acc[mt][nt][r] + bv);
            }
        }
    } else {
        float* part = (blockIdx.z < 5)
            ? (float*)Cv  + (size_t)blockIdx.z * M * N
            : (float*)Cv2 + (size_t)(blockIdx.z - 5) * M * N;
        #pragma unroll
        for (int mt = 0; mt < 8; ++mt) {
            int rg = bm * 256 + wr * 128 + mt * 16 + quad * 4;
            #pragma unroll
            for (int nt = 0; nt < 4; ++nt) {
                int cg = bn * 256 + wc * 64 + nt * 16 + l16;
                #pragma unroll
                for (int r = 0; r < 4; ++r)
                    part[(size_t)(rg + r) * N + cg] = acc[mt][nt][r];
            }
        }
    }
}

#undef KTILE
#undef MMAQ
#undef LDB_PAIR
#undef LDA_HALF
#undef STAGE_B
#undef STAGE_A
#undef WAITL0
#undef BARRIER
#undef CFENCE

// ---------------- split-K reduce + bias + gate + residual -> f32 out ---------
__global__ __launch_bounds__(256)
void reduce_out(const float* __restrict__ pA, const float* __restrict__ pB,
                const float* __restrict__ x, const float* __restrict__ mg,
                const float* __restrict__ b2, float* __restrict__ out)
{
    size_t i = ((size_t)blockIdx.x * 256 + threadIdx.x) * 4;
    int col = (int)(i % DIM);
    const size_t S = (size_t)LSEQ * DIM;
    float4 s0 = *(const float4*)(pA + i);
    float4 s1 = *(const float4*)(pA + S + i);
    float4 s2 = *(const float4*)(pA + 2 * S + i);
    float4 s3 = *(const float4*)(pA + 3 * S + i);
    float4 s4 = *(const float4*)(pA + 4 * S + i);
    float4 s5 = *(const float4*)(pB + i);
    float4 s6 = *(const float4*)(pB + S + i);
    float4 s7 = *(const float4*)(pB + 2 * S + i);
    float4 xb = *(const float4*)(x + i);
    float4 g  = *(const float4*)(mg + col);
    float4 bb = *(const float4*)(b2 + col);
    float4 o;
    o.x = xb.x + g.x * (s0.x + s1.x + s2.x + s3.x + s4.x + s5.x + s6.x + s7.x + bb.x);
    o.y = xb.y + g.y * (s0.y + s1.y + s2.y + s3.y + s4.y + s5.y + s6.y + s7.y + bb.y);
    o.z = xb.z + g.z * (s0.z + s1.z + s2.z + s3.z + s4.z + s5.z + s6.z + s7.z + bb.z);
    o.w = xb.w + g.w * (s0.w + s1.w + s2.w + s3.w + s4.w + s5.w + s6.w + s7.w + bb.w);
    *(float4*)(out + i) = o;
}

// ---------------- q/k RMSNorm + RoPE, in place in fused (bf16) ----------------
__global__ __launch_bounds__(128)
void qkv_post(ushort_t* __restrict__ fused, const float* __restrict__ pe,
              const float* __restrict__ qw, const float* __restrict__ kw)
{
    int l = blockIdx.x, h = blockIdx.y, d = threadIdx.x;
    size_t qoff = (size_t)l * NFUSE + h * HD + d;
    size_t koff = qoff + DIM;
    float q = b2f(fused[qoff]), k = b2f(fused[koff]);
    float sq = q * q, sk = k * k;
    for (int off = 1; off <= 32; off <<= 1) {
        sq += __shfl_xor(sq, off, 64);
        sk += __shfl_xor(sk, off, 64);
    }
    __shared__ float red[4];
    int w = threadIdx.x >> 6;
    if ((threadIdx.x & 63) == 0) { red[w * 2] = sq; red[w * 2 + 1] = sk; }
    __syncthreads();
    float ssq = red[0] + red[2], ssk = red[1] + red[3];
    float rq = rsqrtf(ssq * (1.f / HD) + 1e-6f);
    float rk = rsqrtf(ssk * (1.f / HD) + 1e-6f);
    float qn = q * rq * qw[d];
    float kn = k * rk * kw[d];
    __shared__ float qs[HD], ks_[HD];
    qs[d] = qn; ks_[d] = kn;
    __syncthreads();
    float qr = (d < 64) ? -qs[d + 64] : qs[d - 64];
    float kr = (d < 64) ? -ks_[d + 64] : ks_[d - 64];
    float f = pe[l * HD + d];
    float c = cosf(f), s = sinf(f);
    fused[qoff] = f2b(qn * c + qr * s);
    fused[koff] = f2b(kn * c + kr * s);
}

// ---------------- V transpose: fused V slice -> vT[h][d][seq] (bf16) ---------
__global__ __launch_bounds__(256)
void v_transpose(const ushort_t* __restrict__ fused, ushort_t* __restrict__ vt)
{
    __shared__ ushort_t tile[64 * 136];   // [l][d], padded
    int h = blockIdx.y, l0 = blockIdx.x * 64, tid = threadIdx.x;
    for (int rnd = 0; rnd < 4; ++rnd) {
        int idx = rnd * 256 + tid;            // 0..1023
        int r = idx >> 4, cg = (idx & 15) * 8;
        uint4 dv = *(const uint4*)(fused + (size_t)(l0 + r) * NFUSE + 2 * DIM + h * HD + cg);
        *(uint4*)&tile[r * 136 + cg] = dv;
    }
    __syncthreads();
    for (int rnd = 0; rnd < 4; ++rnd) {
        int idx = rnd * 256 + tid;            // 0..1023
        int d = idx >> 3, jg = (idx & 7) * 8;
        ushort_t o[8];
        for (int t = 0; t < 8; ++t) o[t] = tile[(jg + t) * 136 + d];
        *(uint4*)(vt + (size_t)(h * HD + d) * LSEQ + l0 + jg) = *(uint4*)o;
    }
}

// ---------------- flash attention: Br=64, Bc=64, one head per blockIdx.y ------
__global__ __launch_bounds__(256)
void flash_attn(const ushort_t* __restrict__ fused, const ushort_t* __restrict__ vt,
                ushort_t* __restrict__ comb)
{
    __shared__ ushort_t Qs[4 * 64 * 32];   // [kchunk][row][32]
    __shared__ ushort_t Ks[4 * 64 * 32];
    __shared__ ushort_t Vt2[2 * 128 * 32]; // [jchunk][d][32]
    __shared__ ushort_t Ps[64 * 72];       // padded +8
    int lane = threadIdx.x & 63, w = threadIdx.x >> 6;
    int quad = lane >> 4, l16 = lane & 15;
    int h = blockIdx.y;
    int q0 = blockIdx.x * 64;
    const float scale = 0.08838834764831845f;  // 128^-0.5
    int srow = lane >> 2, scol = (lane & 3) * 8;

    for (int j = 0; j < 4; ++j) {
        int c = w * 4 + j;
        int ks = c >> 2, r = (c & 3) * 16 + srow;
        async_cp16(fused + (size_t)(q0 + r) * NFUSE + h * HD + ks * 32 + scol,
                   &Qs[c * 512 + lane * 8]);
    }

    float m_run[4], l_run[4];
    f32x4 o_acc[8] = {};
    for (int r = 0; r < 4; ++r) { m_run[r] = -1e30f; l_run[r] = 0.f; }

    for (int kt = 0; kt < LSEQ / 64; ++kt) {
        int k0 = kt * 64;
        for (int j = 0; j < 4; ++j) {
            int c = w * 4 + j;
            int ks = c >> 2, r = (c & 3) * 16 + srow;
            async_cp16(fused + (size_t)(k0 + r) * NFUSE + DIM + h * HD + ks * 32 + scol,
                       &Ks[c * 512 + lane * 8]);
        }
        // V tile: rows d (128), cols k0..k0+63, chunked [jc][d][32]
        for (int j = 0; j < 4; ++j) {
            int c = w * 4 + j;                 // 0..15
            int jc = c >> 3, dd = (c & 7) * 16 + srow;
            async_cp16(vt + (size_t)(h * HD + dd) * LSEQ + k0 + jc * 32 + scol,
                       &Vt2[c * 512 + lane * 8]);
        }
        __syncthreads();

        f32x4 s_acc[4] = {};
        bf16x8 aq[4];
        for (int ks = 0; ks < 4; ++ks)
            aq[ks] = *(const bf16x8*)&Qs[ks * 2048 + (w * 16 + l16) * 32 + quad * 8];
        for (int nt = 0; nt < 4; ++nt)
            for (int ks = 0; ks < 4; ++ks) {
                bf16x8 bk = *(const bf16x8*)&Ks[ks * 2048 + (nt * 16 + l16) * 32 + quad * 8];
                s_acc[nt] = __builtin_amdgcn_mfma_f32_16x16x32_bf16(aq[ks], bk, s_acc[nt], 0, 0, 0);
            }
        float alpha[4], rs[4];
        for (int nt = 0; nt < 4; ++nt)
            for (int r = 0; r < 4; ++r) s_acc[nt][r] *= scale;
        for (int r = 0; r < 4; ++r) {
            float m = fmaxf(fmaxf(s_acc[0][r], s_acc[1][r]), fmaxf(s_acc[2][r], s_acc[3][r]));
            for (int off = 8; off >= 1; off >>= 1) m = fmaxf(m, __shfl_xor(m, off, 64));
            float mn = fmaxf(m_run[r], m);
            alpha[r] = __expf(m_run[r] - mn);
            m_run[r] = mn;
            rs[r] = 0.f;
        }
        for (int nt = 0; nt < 4; ++nt)
            for (int r = 0; r < 4; ++r) {
                float p = __expf(s_acc[nt][r] - m_run[r]);
                rs[r] += p;
                Ps[(w * 16 + quad * 4 + r) * 72 + nt * 16 + l16] = f2b(p);
            }
        for (int r = 0; r < 4; ++r) {
            float t = rs[r];
            for (int off = 8; off >= 1; off >>= 1) t += __shfl_xor(t, off, 64);
            l_run[r] = l_run[r] * alpha[r] + t;
        }
        for (int nt2 = 0; nt2 < 8; ++nt2)
            for (int r = 0; r < 4; ++r) o_acc[nt2][r] *= alpha[r];
        __syncthreads();

        bf16x8 ap[2];
        for (int ks2 = 0; ks2 < 2; ++ks2)
            ap[ks2] = *(const bf16x8*)&Ps[(w * 16 + l16) * 72 + ks2 * 32 + quad * 8];
        for (int nt2 = 0; nt2 < 8; ++nt2)
            for (int ks2 = 0; ks2 < 2; ++ks2) {
                bf16x8 bv = *(const bf16x8*)&Vt2[ks2 * 4096 + (nt2 * 16 + l16) * 32 + quad * 8];
                o_acc[nt2] = __builtin_amdgcn_mfma_f32_16x16x32_bf16(ap[ks2], bv, o_acc[nt2], 0, 0, 0);
            }
        __syncthreads();
    }

    for (int nt2 = 0; nt2 < 8; ++nt2) {
        int d = nt2 * 16 + l16;
        for (int r = 0; r < 4; ++r) {
            int ql = q0 + w * 16 + quad * 4 + r;
            comb[(size_t)ql * NCOMB + h * HD + d] = f2b(o_acc[nt2][r] / l_run[r]);
        }
    }
}

// ---------------- GELU (tanh approx) on mlp slice ----------------
__global__ __launch_bounds__(256)
void gelu_k(const ushort_t* __restrict__ fused, ushort_t* __restrict__ comb)
{
    int l = blockIdx.y;
    int oct = blockIdx.x * 256 + threadIdx.x;   // 0..1535
    size_t jo = (size_t)oct * 8;
    const ushort_t* gp = fused + (size_t)l * NFUSE + 3 * DIM + jo;
    uint4 dv = *(const uint4*)gp;
    const ushort_t* u = (const ushort_t*)&dv;
    ushort_t ov[8];
    for (int i = 0; i < 8; ++i) {
        float xv = b2f(u[i]);
        float t = 0.7978845608028654f * (xv + 0.044715f * xv * xv * xv);
        float g = 0.5f * xv * (1.f + tanhf(t));
        ov[i] = f2b(g);
    }
    *(uint4*)(comb + (size_t)l * NCOMB + DIM + jo) = *(uint4*)ov;
}

extern "C" void kernel_launch(void* const* d_in, const int* in_sizes, int n_in,
                              void* d_out, int out_size, void* d_ws, size_t ws_size,
                              hipStream_t stream)
{
    const float* x   = (const float*)d_in[0];
    const float* pe  = (const float*)d_in[1];
    const float* msc = (const float*)d_in[2];
    const float* msh = (const float*)d_in[3];
    const float* mg  = (const float*)d_in[4];
    // d_in[5] = mask (all zeros) — unused
    const float* W1  = (const float*)d_in[6];
    const float* b1  = (const float*)d_in[7];
    const float* qw  = (const float*)d_in[8];
    const float* kw  = (const float*)d_in[9];
    const float* W2  = (const float*)d_in[10];
    const float* b2  = (const float*)d_in[11];
    float* out = (float*)d_out;

    // ws layout (bf16 scratch): W1b | W2b | fused | comb   (~377.5 MB)
    ushort_t* W1b   = (ushort_t*)d_ws;                        // 21504*3072
    ushort_t* W2b   = W1b + (size_t)NFUSE * DIM;              // 3072*15360
    ushort_t* fused = W2b + (size_t)DIM * NCOMB;              // 2048*21504
    ushort_t* comb  = fused + (size_t)LSEQ * NFUSE;           // 2048*15360
    // d_out (25.2MB) doubles as scratch: first half xmod (dead after gemm1),
    // second half vT (written after gemm1, dead after flash). reduce_out
    // overwrites d_out last.
    ushort_t* xmod  = (ushort_t*)d_out;                       // 2048*3072 bf16
    ushort_t* vT    = xmod + (size_t)LSEQ * DIM;              // 3072*2048 bf16
    // split-K(8) partials: z 0..4 alias W1b (5*25.2=125.8MB <= 132.1MB),
    // z 5..7 alias fused (3*25.2=75.5MB <= 88.1MB). Both dead at gemm2 time.
    float* partsA   = (float*)W1b;
    float* partsB   = (float*)fused;

    cast_f2b<<<(NFUSE * DIM) / 1024, 256, 0, stream>>>(W1, W1b);
    cast_f2b<<<(DIM * NCOMB) / 1024, 256, 0, stream>>>(W2, W2b);
    ln_mod<<<LSEQ, 256, 0, stream>>>(x, msc, msh, xmod);
    gemm8p<0><<<dim3(NFUSE / 256, LSEQ / 256, 1), 512, 0, stream>>>(
        xmod, W1b, b1, fused, nullptr, LSEQ, NFUSE, DIM, DIM);
    qkv_post<<<dim3(LSEQ, HEADS), 128, 0, stream>>>(fused, pe, qw, kw);
    v_transpose<<<dim3(LSEQ / 64, HEADS), 256, 0, stream>>>(fused, vT);
    flash_attn<<<dim3(LSEQ / 64, HEADS), 256, 0, stream>>>(fused, vT, comb);
    gelu_k<<<dim3(6, LSEQ), 256, 0, stream>>>(fused, comb);
    gemm8p<2><<<dim3(DIM / 256, LSEQ / 256, 8), 512, 0, stream>>>(
        comb, W2b, nullptr, partsA, partsB, LSEQ, DIM, NCOMB, NCOMB / 8);
    reduce_out<<<(LSEQ * DIM) / 1024, 256, 0, stream>>>(partsA, partsB, x, mg, b2, out);
}

// Round 2
// 1196.026 us; speedup vs baseline: 1.1509x; 1.0267x over previous
//
#include <hip/hip_runtime.h>
#include <hip/hip_bf16.h>
#include <cstdint>

typedef unsigned short ushort_t;
typedef __attribute__((ext_vector_type(8))) short bf16x8;
typedef __attribute__((ext_vector_type(4))) float f32x4;

#define LSEQ 2048
#define DIM 3072
#define NFUSE 21504   // 3*DIM + MLP
#define NCOMB 15360   // DIM + MLP
#define HEADS 24
#define HD 128

__device__ __forceinline__ float b2f(ushort_t u) {
    union { float f; unsigned v; } x; x.v = ((unsigned)u) << 16; return x.f;
}
__device__ __forceinline__ ushort_t f2b(float f) {
    union { float f; unsigned v; } x; x.f = f;
    unsigned r = (x.v + 0x7FFF + ((x.v >> 16) & 1)) >> 16;
    return (ushort_t)r;
}
__device__ __forceinline__ void async_cp16(const void* g, void* l) {
    __builtin_amdgcn_global_load_lds(
        (const __attribute__((address_space(1))) void*)g,
        (__attribute__((address_space(3))) void*)l, 16, 0, 0);
}

// ---------------- f32 -> bf16 cast (weights) ----------------
__global__ __launch_bounds__(256)
void cast_f2b(const float* __restrict__ src, ushort_t* __restrict__ dst)
{
    size_t i = ((size_t)blockIdx.x * 256 + threadIdx.x) * 4;
    float4 v = *(const float4*)(src + i);
    ushort_t o[4] = { f2b(v.x), f2b(v.y), f2b(v.z), f2b(v.w) };
    *(uint2*)(dst + i) = *(uint2*)o;
}

// ---------------- LayerNorm + modulation (f32 in, bf16 out) ----------------
__global__ __launch_bounds__(256)
void ln_mod(const float* __restrict__ x, const float* __restrict__ msc,
            const float* __restrict__ msh, ushort_t* __restrict__ xmod)
{
    int l = blockIdx.x, t = threadIdx.x;
    const float* xr = x + (size_t)l * DIM;
    float v[12]; float s = 0.f;
    for (int i = 0; i < 12; ++i) { v[i] = xr[t + i * 256]; s += v[i]; }
    for (int off = 1; off <= 32; off <<= 1) s += __shfl_xor(s, off, 64);
    __shared__ float red[8];
    int w = t >> 6;
    if ((t & 63) == 0) red[w] = s;
    __syncthreads();
    s = red[0] + red[1] + red[2] + red[3];
    float mu = s * (1.f / DIM);
    float vs = 0.f;
    for (int i = 0; i < 12; ++i) { float d = v[i] - mu; vs += d * d; }
    for (int off = 1; off <= 32; off <<= 1) vs += __shfl_xor(vs, off, 64);
    if ((t & 63) == 0) red[4 + w] = vs;
    __syncthreads();
    vs = red[4] + red[5] + red[6] + red[7];
    float rinv = rsqrtf(vs * (1.f / DIM) + 1e-6f);
    ushort_t* orow = xmod + (size_t)l * DIM;
    for (int i = 0; i < 12; ++i) {
        int c = t + i * 256;
        float m = (v[i] - mu) * rinv;
        orow[c] = f2b((1.f + msc[c]) * m + msh[c]);
    }
}

// ============ 256x256-tile, BK=64, 8-wave, 8-phase pipelined GEMM =============
// C[M,N] = A[M,K] * B[N,K]^T.  MODE 0: bf16 C + bias.  MODE 2: f32 split-K
// partials (z<5 -> Cv, z>=5 -> Cv2).  Requires M%256==0, N%256==0,
// kchunk%128==0 (NT even, NT>=2), grid.x*grid.y % 8 == 0.
//
// LDS (128 KiB): buf b at b*32768 ushorts; A at +0, B at +16384.
// Chunk = 16 rows x 32 cols bf16 = 1 KiB = one wave64 global_load_lds x16 round.
// Within chunk: row-major [16][4 slots of 8], with T2 XOR-swizzle:
//   stored(row, slot) holds logical (row, slot ^ ((row>>1)&3)).
// Write side: LDS dest is linear (global_load_lds constraint, rule #21); the
//   swizzle is realized by pre-permuting the per-lane GLOBAL source column:
//   scol = ((lane&3) ^ ((lane>>3)&3))*8   (srow = lane>>2, so (lane>>3)&3 =
//   (srow>>1)&3). Read side: slot' = quad ^ ((l16>>1)&3) — per-thread constant.
// Result: any 16 consecutive lanes of a ds_read_b128 cover all 32 banks at
//   2 dwords/bank (2-way = free, m136), vs 8-way for the linear layout.
//
// Per K-tile (4 phases; quadrants of the 8x4 per-wave frag grid):
//  ph1: ds_read A[m0-3] (8) + B[n0-1] (4); stage t+1 B-half0 -> nxt
//  ph2: ds_read B[n2-3] (4);               stage t+1 B-half1 -> nxt
//  ph3: ds_read A[m4-7] (8, reuse regs);   (no stage)
//  ph4: stage t+2 A-half0+half1 -> cur (safe: all reads of cur done at ph3 bar);
//       MFMA; s_waitcnt vmcnt(4); barrier   (t+1 fully landed, t+2 A in flight)
// Steady state: 8 loads issued/tile, vmcnt(4) leaves 2 half-tiles in flight.

#define CFENCE() asm volatile("" ::: "memory")
#define BARRIER() do { CFENCE(); __builtin_amdgcn_s_barrier(); CFENCE(); } while (0)
#define WAITL0() asm volatile("s_waitcnt lgkmcnt(0)" ::: "memory")

#define STAGE_A(bf, hf, kt) do { \
    const ushort_t* _s = Ag + (size_t)(hf) * 128 * Ks + (size_t)(kt) * 64; \
    async_cp16(_s,                   &Lds[(bf) * 32768 + (hf) * 4096 + stA]); \
    async_cp16(_s + (size_t)64 * Ks, &Lds[(bf) * 32768 + (hf) * 4096 + stA + 2048]); \
} while (0)

#define STAGE_B(bf, hf, kt) do { \
    const ushort_t* _s = Bg + (size_t)(hf) * 128 * Ks + (size_t)(kt) * 64; \
    async_cp16(_s,                   &Lds[(bf) * 32768 + (hf) * 4096 + stB]); \
    async_cp16(_s + (size_t)64 * Ks, &Lds[(bf) * 32768 + (hf) * 4096 + stB + 2048]); \
} while (0)

#define LDA_HALF(bf, mbase) do { \
    _Pragma("unroll") for (int _mt = 0; _mt < 4; ++_mt) { \
        af[_mt][0] = *(const bf16x8*)&Lds[(bf) * 32768 +        rdA + ((mbase) + _mt) * 512]; \
        af[_mt][1] = *(const bf16x8*)&Lds[(bf) * 32768 + 8192 + rdA + ((mbase) + _mt) * 512]; \
    } } while (0)

#define LDB_PAIR(bf, nbase) do { \
    _Pragma("unroll") for (int _nt = 0; _nt < 2; ++_nt) { \
        bfr[(nbase) + _nt][0] = *(const bf16x8*)&Lds[(bf) * 32768 +        rdB + ((nbase) + _nt) * 512]; \
        bfr[(nbase) + _nt][1] = *(const bf16x8*)&Lds[(bf) * 32768 + 8192 + rdB + ((nbase) + _nt) * 512]; \
    } } while (0)

#define MMAQ(mlo, nlo) do { \
    _Pragma("unroll") for (int _mt = 0; _mt < 4; ++_mt) \
    _Pragma("unroll") for (int _nt = 0; _nt < 2; ++_nt) { \
        acc[(mlo) + _mt][(nlo) + _nt] = __builtin_amdgcn_mfma_f32_16x16x32_bf16( \
            af[_mt][0], bfr[(nlo) + _nt][0], acc[(mlo) + _mt][(nlo) + _nt], 0, 0, 0); \
        acc[(mlo) + _mt][(nlo) + _nt] = __builtin_amdgcn_mfma_f32_16x16x32_bf16( \
            af[_mt][1], bfr[(nlo) + _nt][1], acc[(mlo) + _mt][(nlo) + _nt], 0, 0, 0); \
    } } while (0)

#define KTILE(cur, nxt, t) do { \
    int _t1 = ((t) + 1 < NT) ? (t) + 1 : NT - 1; \
    int _t2 = ((t) + 2 < NT) ? (t) + 2 : NT - 1; \
    /* phase 1 */ \
    LDA_HALF(cur, 0); LDB_PAIR(cur, 0); \
    STAGE_B(nxt, 0, _t1); \
    asm volatile("s_waitcnt lgkmcnt(8)" ::: "memory"); \
    BARRIER(); WAITL0(); \
    __builtin_amdgcn_s_setprio(1); MMAQ(0, 0); __builtin_amdgcn_s_setprio(0); \
    BARRIER(); \
    /* phase 2 */ \
    LDB_PAIR(cur, 2); \
    STAGE_B(nxt, 1, _t1); \
    BARRIER(); WAITL0(); \
    __builtin_amdgcn_s_setprio(1); MMAQ(0, 2); __builtin_amdgcn_s_setprio(0); \
    BARRIER(); \
    /* phase 3 */ \
    LDA_HALF(cur, 4); \
    BARRIER(); WAITL0(); \
    __builtin_amdgcn_s_setprio(1); MMAQ(4, 2); __builtin_amdgcn_s_setprio(0); \
    BARRIER(); \
    /* phase 4 (no ds_reads; stage into cur is safe after ph3 barrier) */ \
    STAGE_A(cur, 0, _t2); STAGE_A(cur, 1, _t2); \
    __builtin_amdgcn_s_setprio(1); MMAQ(4, 0); __builtin_amdgcn_s_setprio(0); \
    asm volatile("s_waitcnt vmcnt(4)" ::: "memory"); \
    BARRIER(); \
} while (0)

template<int MODE>
__global__ __launch_bounds__(512, 2)
void gemm8p(const ushort_t* __restrict__ A, const ushort_t* __restrict__ B,
            const float* __restrict__ bias, void* __restrict__ Cv,
            void* __restrict__ Cv2, int M, int N, int Ks, int kchunk)
{
    __shared__ ushort_t Lds[65536];   // 128 KiB
    const int lane = threadIdx.x & 63, w = threadIdx.x >> 6;
    const int quad = lane >> 4, l16 = lane & 15;
    const int srow = lane >> 2;
    const int scol = (((lane & 3) ^ ((lane >> 3) & 3)) * 8);   // T2 pre-permute
    const int wr = w >> 2, wc = w & 3;
    const int kcS = w & 1, rc0 = w >> 1;   // staging chunk assignment

    // XCD-aware swizzle (nwg % 8 == 0 for all launches here)
    int nwg = gridDim.x * gridDim.y;
    int id = blockIdx.y * gridDim.x + blockIdx.x;
    int cpx = nwg >> 3;
    int swz = (id & 7) * cpx + (id >> 3);
    int bn = swz % gridDim.x, bm = swz / gridDim.x;

    const int kbeg = blockIdx.z * kchunk;
    const int NT = kchunk >> 6;

    const ushort_t* Ag = A + (size_t)bm * 256 * Ks + (size_t)(rc0 * 16 + srow) * Ks
                           + kbeg + kcS * 32 + scol;
    const ushort_t* Bg = B + (size_t)bn * 256 * Ks + (size_t)(rc0 * 16 + srow) * Ks
                           + kbeg + kcS * 32 + scol;

    const int stA = kcS * 8192 + rc0 * 512 + lane * 8;
    const int stB = 16384 + stA;
    const int cswz = ((quad ^ ((l16 >> 1) & 3)) * 8);          // T2 read swizzle
    const int rdA = wr * 4096 + l16 * 32 + cswz;
    const int rdB = 16384 + wc * 2048 + l16 * 32 + cswz;

    f32x4 acc[8][4] = {};
    bf16x8 af[4][2], bfr[4][2];

    // prologue: tile0 A+B -> buf0, tile1 A -> buf1; drain tile0 (vmcnt(4))
    STAGE_A(0, 0, 0); STAGE_A(0, 1, 0);
    STAGE_B(0, 0, 0); STAGE_B(0, 1, 0);
    STAGE_A(1, 0, 1); STAGE_A(1, 1, 1);
    asm volatile("s_waitcnt vmcnt(4)" ::: "memory");
    BARRIER();

    for (int t = 0; t < NT; t += 2) {
        KTILE(0, 1, t);
        KTILE(1, 0, t + 1);
    }
    asm volatile("s_waitcnt vmcnt(0)" ::: "memory");

    if constexpr (MODE == 0) {
        ushort_t* C = (ushort_t*)Cv;
        #pragma unroll
        for (int mt = 0; mt < 8; ++mt) {
            int rg = bm * 256 + wr * 128 + mt * 16 + quad * 4;
            #pragma unroll
            for (int nt = 0; nt < 4; ++nt) {
                int cg = bn * 256 + wc * 64 + nt * 16 + l16;
                float bv = bias[cg];
                #pragma unroll
                for (int r = 0; r < 4; ++r)
                    C[(size_t)(rg + r) * N + cg] = f2b(acc[mt][nt][r] + bv);
            }
        }
    } else {
        float* part = (blockIdx.z < 5)
            ? (float*)Cv  + (size_t)blockIdx.z * M * N
            : (float*)Cv2 + (size_t)(blockIdx.z - 5) * M * N;
        #pragma unroll
        for (int mt = 0; mt < 8; ++mt) {
            int rg = bm * 256 + wr * 128 + mt * 16 + quad * 4;
            #pragma unroll
            for (int nt = 0; nt < 4; ++nt) {
                int cg = bn * 256 + wc * 64 + nt * 16 + l16;
                #pragma unroll
                for (int r = 0; r < 4; ++r)
                    part[(size_t)(rg + r) * N + cg] = acc[mt][nt][r];
            }
        }
    }
}

#undef KTILE
#undef MMAQ
#undef LDB_PAIR
#undef LDA_HALF
#undef STAGE_B
#undef STAGE_A
#undef WAITL0
#undef BARRIER
#undef CFENCE

// ---------------- split-K reduce + bias + gate + residual -> f32 out ---------
__global__ __launch_bounds__(256)
void reduce_out(const float* __restrict__ pA, const float* __restrict__ pB,
                const float* __restrict__ x, const float* __restrict__ mg,
                const float* __restrict__ b2, float* __restrict__ out)
{
    size_t i = ((size_t)blockIdx.x * 256 + threadIdx.x) * 4;
    int col = (int)(i % DIM);
    const size_t S = (size_t)LSEQ * DIM;
    float4 s0 = *(const float4*)(pA + i);
    float4 s1 = *(const float4*)(pA + S + i);
    float4 s2 = *(const float4*)(pA + 2 * S + i);
    float4 s3 = *(const float4*)(pA + 3 * S + i);
    float4 s4 = *(const float4*)(pA + 4 * S + i);
    float4 s5 = *(const float4*)(pB + i);
    float4 s6 = *(const float4*)(pB + S + i);
    float4 s7 = *(const float4*)(pB + 2 * S + i);
    float4 xb = *(const float4*)(x + i);
    float4 g  = *(const float4*)(mg + col);
    float4 bb = *(const float4*)(b2 + col);
    float4 o;
    o.x = xb.x + g.x * (s0.x + s1.x + s2.x + s3.x + s4.x + s5.x + s6.x + s7.x + bb.x);
    o.y = xb.y + g.y * (s0.y + s1.y + s2.y + s3.y + s4.y + s5.y + s6.y + s7.y + bb.y);
    o.z = xb.z + g.z * (s0.z + s1.z + s2.z + s3.z + s4.z + s5.z + s6.z + s7.z + bb.z);
    o.w = xb.w + g.w * (s0.w + s1.w + s2.w + s3.w + s4.w + s5.w + s6.w + s7.w + bb.w);
    *(float4*)(out + i) = o;
}

// ---------------- q/k RMSNorm + RoPE, in place in fused (bf16) ----------------
__global__ __launch_bounds__(128)
void qkv_post(ushort_t* __restrict__ fused, const float* __restrict__ pe,
              const float* __restrict__ qw, const float* __restrict__ kw)
{
    int l = blockIdx.x, h = blockIdx.y, d = threadIdx.x;
    size_t qoff = (size_t)l * NFUSE + h * HD + d;
    size_t koff = qoff + DIM;
    float q = b2f(fused[qoff]), k = b2f(fused[koff]);
    float sq = q * q, sk = k * k;
    for (int off = 1; off <= 32; off <<= 1) {
        sq += __shfl_xor(sq, off, 64);
        sk += __shfl_xor(sk, off, 64);
    }
    __shared__ float red[4];
    int w = threadIdx.x >> 6;
    if ((threadIdx.x & 63) == 0) { red[w * 2] = sq; red[w * 2 + 1] = sk; }
    __syncthreads();
    float ssq = red[0] + red[2], ssk = red[1] + red[3];
    float rq = rsqrtf(ssq * (1.f / HD) + 1e-6f);
    float rk = rsqrtf(ssk * (1.f / HD) + 1e-6f);
    float qn = q * rq * qw[d];
    float kn = k * rk * kw[d];
    __shared__ float qs[HD], ks_[HD];
    qs[d] = qn; ks_[d] = kn;
    __syncthreads();
    float qr = (d < 64) ? -qs[d + 64] : qs[d - 64];
    float kr = (d < 64) ? -ks_[d + 64] : ks_[d - 64];
    float f = pe[l * HD + d];
    float c = cosf(f), s = sinf(f);
    fused[qoff] = f2b(qn * c + qr * s);
    fused[koff] = f2b(kn * c + kr * s);
}

// ---------------- V transpose: fused V slice -> vT[h][d][seq] (bf16) ---------
__global__ __launch_bounds__(256)
void v_transpose(const ushort_t* __restrict__ fused, ushort_t* __restrict__ vt)
{
    __shared__ ushort_t tile[64 * 136];   // [l][d], padded
    int h = blockIdx.y, l0 = blockIdx.x * 64, tid = threadIdx.x;
    for (int rnd = 0; rnd < 4; ++rnd) {
        int idx = rnd * 256 + tid;            // 0..1023
        int r = idx >> 4, cg = (idx & 15) * 8;
        uint4 dv = *(const uint4*)(fused + (size_t)(l0 + r) * NFUSE + 2 * DIM + h * HD + cg);
        *(uint4*)&tile[r * 136 + cg] = dv;
    }
    __syncthreads();
    for (int rnd = 0; rnd < 4; ++rnd) {
        int idx = rnd * 256 + tid;            // 0..1023
        int d = idx >> 3, jg = (idx & 7) * 8;
        ushort_t o[8];
        for (int t = 0; t < 8; ++t) o[t] = tile[(jg + t) * 136 + d];
        *(uint4*)(vt + (size_t)(h * HD + d) * LSEQ + l0 + jg) = *(uint4*)o;
    }
}

// ---------------- flash attention: Br=64, Bc=64, one head per blockIdx.y ------
// Same T2 chunk swizzle as gemm8p on Qs/Ks/Vt2 (staged via global_load_lds:
// pre-permuted global source col + swizzled read slot). Ps is stride-72
// (2-way free) and written with scalar stores — left linear.
__global__ __launch_bounds__(256)
void flash_attn(const ushort_t* __restrict__ fused, const ushort_t* __restrict__ vt,
                ushort_t* __restrict__ comb)
{
    __shared__ ushort_t Qs[4 * 64 * 32];   // [kchunk][row][32]
    __shared__ ushort_t Ks[4 * 64 * 32];
    __shared__ ushort_t Vt2[2 * 128 * 32]; // [jchunk][d][32]
    __shared__ ushort_t Ps[64 * 72];       // padded +8
    int lane = threadIdx.x & 63, w = threadIdx.x >> 6;
    int quad = lane >> 4, l16 = lane & 15;
    int h = blockIdx.y;
    int q0 = blockIdx.x * 64;
    const float scale = 0.08838834764831845f;  // 128^-0.5
    int srow = lane >> 2;
    int scol = ((lane & 3) ^ ((lane >> 3) & 3)) * 8;           // T2 pre-permute
    int cswz = (quad ^ ((l16 >> 1) & 3)) * 8;                  // T2 read swizzle

    for (int j = 0; j < 4; ++j) {
        int c = w * 4 + j;
        int ks = c >> 2, r = (c & 3) * 16 + srow;
        async_cp16(fused + (size_t)(q0 + r) * NFUSE + h * HD + ks * 32 + scol,
                   &Qs[c * 512 + lane * 8]);
    }

    float m_run[4], l_run[4];
    f32x4 o_acc[8] = {};
    for (int r = 0; r < 4; ++r) { m_run[r] = -1e30f; l_run[r] = 0.f; }

    for (int kt = 0; kt < LSEQ / 64; ++kt) {
        int k0 = kt * 64;
        for (int j = 0; j < 4; ++j) {
            int c = w * 4 + j;
            int ks = c >> 2, r = (c & 3) * 16 + srow;
            async_cp16(fused + (size_t)(k0 + r) * NFUSE + DIM + h * HD + ks * 32 + scol,
                       &Ks[c * 512 + lane * 8]);
        }
        // V tile: rows d (128), cols k0..k0+63, chunked [jc][d][32]
        for (int j = 0; j < 4; ++j) {
            int c = w * 4 + j;                 // 0..15
            int jc = c >> 3, dd = (c & 7) * 16 + srow;
            async_cp16(vt + (size_t)(h * HD + dd) * LSEQ + k0 + jc * 32 + scol,
                       &Vt2[c * 512 + lane * 8]);
        }
        __syncthreads();

        f32x4 s_acc[4] = {};
        bf16x8 aq[4];
        for (int ks = 0; ks < 4; ++ks)
            aq[ks] = *(const bf16x8*)&Qs[ks * 2048 + (w * 16 + l16) * 32 + cswz];
        for (int nt = 0; nt < 4; ++nt)
            for (int ks = 0; ks < 4; ++ks) {
                bf16x8 bk = *(const bf16x8*)&Ks[ks * 2048 + (nt * 16 + l16) * 32 + cswz];
                s_acc[nt] = __builtin_amdgcn_mfma_f32_16x16x32_bf16(aq[ks], bk, s_acc[nt], 0, 0, 0);
            }
        float alpha[4], rs[4];
        for (int nt = 0; nt < 4; ++nt)
            for (int r = 0; r < 4; ++r) s_acc[nt][r] *= scale;
        for (int r = 0; r < 4; ++r) {
            float m = fmaxf(fmaxf(s_acc[0][r], s_acc[1][r]), fmaxf(s_acc[2][r], s_acc[3][r]));
            for (int off = 8; off >= 1; off >>= 1) m = fmaxf(m, __shfl_xor(m, off, 64));
            float mn = fmaxf(m_run[r], m);
            alpha[r] = __expf(m_run[r] - mn);
            m_run[r] = mn;
            rs[r] = 0.f;
        }
        for (int nt = 0; nt < 4; ++nt)
            for (int r = 0; r < 4; ++r) {
                float p = __expf(s_acc[nt][r] - m_run[r]);
                rs[r] += p;
                Ps[(w * 16 + quad * 4 + r) * 72 + nt * 16 + l16] = f2b(p);
            }
        for (int r = 0; r < 4; ++r) {
            float t = rs[r];
            for (int off = 8; off >= 1; off >>= 1) t += __shfl_xor(t, off, 64);
            l_run[r] = l_run[r] * alpha[r] + t;
        }
        for (int nt2 = 0; nt2 < 8; ++nt2)
            for (int r = 0; r < 4; ++r) o_acc[nt2][r] *= alpha[r];
        __syncthreads();

        bf16x8 ap[2];
        for (int ks2 = 0; ks2 < 2; ++ks2)
            ap[ks2] = *(const bf16x8*)&Ps[(w * 16 + l16) * 72 + ks2 * 32 + quad * 8];
        for (int nt2 = 0; nt2 < 8; ++nt2)
            for (int ks2 = 0; ks2 < 2; ++ks2) {
                bf16x8 bv = *(const bf16x8*)&Vt2[ks2 * 4096 + (nt2 * 16 + l16) * 32 + cswz];
                o_acc[nt2] = __builtin_amdgcn_mfma_f32_16x16x32_bf16(ap[ks2], bv, o_acc[nt2], 0, 0, 0);
            }
        __syncthreads();
    }

    for (int nt2 = 0; nt2 < 8; ++nt2) {
        int d = nt2 * 16 + l16;
        for (int r = 0; r < 4; ++r) {
            int ql = q0 + w * 16 + quad * 4 + r;
            comb[(size_t)ql * NCOMB + h * HD + d] = f2b(o_acc[nt2][r] / l_run[r]);
        }
    }
}

// ---------------- GELU (tanh approx) on mlp slice ----------------
__global__ __launch_bounds__(256)
void gelu_k(const ushort_t* __restrict__ fused, ushort_t* __restrict__ comb)
{
    int l = blockIdx.y;
    int oct = blockIdx.x * 256 + threadIdx.x;   // 0..1535
    size_t jo = (size_t)oct * 8;
    const ushort_t* gp = fused + (size_t)l * NFUSE + 3 * DIM + jo;
    uint4 dv = *(const uint4*)gp;
    const ushort_t* u = (const ushort_t*)&dv;
    ushort_t ov[8];
    for (int i = 0; i < 8; ++i) {
        float xv = b2f(u[i]);
        float t = 0.7978845608028654f * (xv + 0.044715f * xv * xv * xv);
        float g = 0.5f * xv * (1.f + tanhf(t));
        ov[i] = f2b(g);
    }
    *(uint4*)(comb + (size_t)l * NCOMB + DIM + jo) = *(uint4*)ov;
}

extern "C" void kernel_launch(void* const* d_in, const int* in_sizes, int n_in,
                              void* d_out, int out_size, void* d_ws, size_t ws_size,
                              hipStream_t stream)
{
    const float* x   = (const float*)d_in[0];
    const float* pe  = (const float*)d_in[1];
    const float* msc = (const float*)d_in[2];
    const float* msh = (const float*)d_in[3];
    const float* mg  = (const float*)d_in[4];
    // d_in[5] = mask (all zeros) — unused
    const float* W1  = (const float*)d_in[6];
    const float* b1  = (const float*)d_in[7];
    const float* qw  = (const float*)d_in[8];
    const float* kw  = (const float*)d_in[9];
    const float* W2  = (const float*)d_in[10];
    const float* b2  = (const float*)d_in[11];
    float* out = (float*)d_out;

    // ws layout (bf16 scratch): W1b | W2b | fused | comb   (~377.5 MB)
    ushort_t* W1b   = (ushort_t*)d_ws;                        // 21504*3072
    ushort_t* W2b   = W1b + (size_t)NFUSE * DIM;              // 3072*15360
    ushort_t* fused = W2b + (size_t)DIM * NCOMB;              // 2048*21504
    ushort_t* comb  = fused + (size_t)LSEQ * NFUSE;           // 2048*15360
    // d_out (25.2MB) doubles as scratch: first half xmod (dead after gemm1),
    // second half vT (written after gemm1, dead after flash). reduce_out
    // overwrites d_out last.
    ushort_t* xmod  = (ushort_t*)d_out;                       // 2048*3072 bf16
    ushort_t* vT    = xmod + (size_t)LSEQ * DIM;              // 3072*2048 bf16
    // split-K(8) partials: z 0..4 alias W1b (5*25.2=125.8MB <= 132.1MB),
    // z 5..7 alias fused (3*25.2=75.5MB <= 88.1MB). Both dead at gemm2 time.
    float* partsA   = (float*)W1b;
    float* partsB   = (float*)fused;

    cast_f2b<<<(NFUSE * DIM) / 1024, 256, 0, stream>>>(W1, W1b);
    cast_f2b<<<(DIM * NCOMB) / 1024, 256, 0, stream>>>(W2, W2b);
    ln_mod<<<LSEQ, 256, 0, stream>>>(x, msc, msh, xmod);
    gemm8p<0><<<dim3(NFUSE / 256, LSEQ / 256, 1), 512, 0, stream>>>(
        xmod, W1b, b1, fused, nullptr, LSEQ, NFUSE, DIM, DIM);
    qkv_post<<<dim3(LSEQ, HEADS), 128, 0, stream>>>(fused, pe, qw, kw);
    v_transpose<<<dim3(LSEQ / 64, HEADS), 256, 0, stream>>>(fused, vT);
    flash_attn<<<dim3(LSEQ / 64, HEADS), 256, 0, stream>>>(fused, vT, comb);
    gelu_k<<<dim3(6, LSEQ), 256, 0, stream>>>(fused, comb);
    gemm8p<2><<<dim3(DIM / 256, LSEQ / 256, 8), 512, 0, stream>>>(
        comb, W2b, nullptr, partsA, partsB, LSEQ, DIM, NCOMB, NCOMB / 8);
    reduce_out<<<(LSEQ * DIM) / 1024, 256, 0, stream>>>(partsA, partsB, x, mg, b2, out);
}